// Round 4
// baseline (1897.382 us; speedup 1.0000x reference)
//
#include <hip/hip_runtime.h>
#include <math.h>

typedef unsigned int u32;

__device__ __forceinline__ float leakyf(float x){ return x>=0.f? x : 0.01f*x; }

// ---------------- omic SNN branches ----------------
struct OmicArgs {
    const float* x[6];
    const float* w1[6];
    int s[6];
};

__global__ __launch_bounds__(256) void omic_kernel(OmicArgs oa,
        const float* __restrict__ sb1, const float* __restrict__ sw2,
        const float* __restrict__ sb2, float* __restrict__ out)
{
    int br = blockIdx.x;
    int t = threadIdx.x;
    int s = oa.s[br];
    __shared__ float xs[1536];
    __shared__ float h1[256];
    const float* x = oa.x[br];
    for (int i=t;i<s;i+=256) xs[i] = x[i];
    __syncthreads();
    const float* w1r = oa.w1[br] + (size_t)t * s;
    float a = sb1[br*256+t];
    for (int i=0;i<s;++i) a += xs[i]*w1r[i];
    a = a>0.f ? a : expm1f(a);
    h1[t] = a;
    __syncthreads();
    const float* w2r = sw2 + (size_t)br*65536 + (size_t)t*256;
    float a2 = sb2[br*256+t];
    #pragma unroll 4
    for (int i=0;i<256;++i) a2 += h1[i]*w2r[i];
    a2 = a2>0.f ? a2 : expm1f(a2);
    out[br*256+t] = a2;
}

// ---------------- generic GEMM: C = act(A[M,K] @ W[N,K]^T + b) ----------------
template<int ACT>
__global__ __launch_bounds__(256) void gemm_awt(
    const float* __restrict__ A, const float* __restrict__ W,
    const float* __restrict__ bias, float* __restrict__ C,
    int M, int N, int K)
{
    __shared__ float As[16][68];
    __shared__ float Bs[16][68];
    int tid = threadIdx.x;
    int tx = tid & 15, ty = tid >> 4;
    int bm = blockIdx.y << 6, bn = blockIdx.x << 6;
    int lr = tid >> 2, lc = (tid & 3) << 2;
    float acc[4][4] = {};
    for (int k0=0;k0<K;k0+=16){
        float4 av = *(const float4*)(A + (size_t)(bm+lr)*K + k0 + lc);
        As[lc+0][lr]=av.x; As[lc+1][lr]=av.y; As[lc+2][lr]=av.z; As[lc+3][lr]=av.w;
        float4 wv = *(const float4*)(W + (size_t)(bn+lr)*K + k0 + lc);
        Bs[lc+0][lr]=wv.x; Bs[lc+1][lr]=wv.y; Bs[lc+2][lr]=wv.z; Bs[lc+3][lr]=wv.w;
        __syncthreads();
        #pragma unroll
        for (int k=0;k<16;++k){
            float a[4], b[4];
            #pragma unroll
            for (int i=0;i<4;++i) a[i]=As[k][(ty<<2)+i];
            #pragma unroll
            for (int j=0;j<4;++j) b[j]=Bs[k][(tx<<2)+j];
            #pragma unroll
            for (int i=0;i<4;++i)
                #pragma unroll
                for (int j=0;j<4;++j)
                    acc[i][j] += a[i]*b[j];
        }
        __syncthreads();
    }
    #pragma unroll
    for (int i=0;i<4;++i){
        int rr = bm + (ty<<2) + i;
        #pragma unroll
        for (int j=0;j<4;++j){
            int cc = bn + (tx<<2) + j;
            float vv = acc[i][j] + bias[cc];
            if (ACT==1) vv = leakyf(vv);
            C[(size_t)rr*N + cc] = vv;
        }
    }
}

// ---------------- column mean + h update ----------------
__global__ __launch_bounds__(256) void colmean(const float* __restrict__ H, float* __restrict__ Mc)
{
    __shared__ float red[256];
    int c=blockIdx.x, t=threadIdx.x;
    float s=0;
    for (int i=t;i<8192;i+=256) s += H[(size_t)i*512 + c];
    red[t]=s; __syncthreads();
    for (int o=128;o>0;o>>=1){ if(t<o) red[t]+=red[t+o]; __syncthreads(); }
    if (t==0) Mc[c] = red[0] * (1.0f/8192.0f);
}

__global__ __launch_bounds__(256) void hupd(float* __restrict__ H, const float* __restrict__ Mc)
{
    int i = blockIdx.x*256 + threadIdx.x;
    H[i] = (H[i] + Mc[i & 511]) * 0.5f;
}

// ---------------- fused logits GEMM + top-6 (per column-quarter) ----------------
__global__ __launch_bounds__(256) void logits_topk(
    const float* __restrict__ EH, const float* __restrict__ ET,
    float* __restrict__ VALS, int* __restrict__ IDX)
{
    const int K = 512;
    const float scale = 0.04419417382415922f; // 512^-0.5
    __shared__ float As[16][68];
    __shared__ float Bs[16][68];
    __shared__ float Sc[64][65];
    int tid=threadIdx.x, tx=tid&15, ty=tid>>4;
    int bm = blockIdx.x<<6;
    int base = blockIdx.y*2048;
    int lr=tid>>2, lc=(tid&3)<<2;
    int r = tid & 63, q = tid >> 6;
    float tv[6]; int ti[6];
    #pragma unroll
    for (int k=0;k<6;++k){ tv[k]=-INFINITY; ti[k]=0; }

    for (int bn=base; bn<base+2048; bn+=64){
        float acc[4][4] = {};
        for (int k0=0;k0<K;k0+=16){
            float4 av = *(const float4*)(EH + (size_t)(bm+lr)*K + k0+lc);
            As[lc+0][lr]=av.x*scale; As[lc+1][lr]=av.y*scale; As[lc+2][lr]=av.z*scale; As[lc+3][lr]=av.w*scale;
            float4 bv = *(const float4*)(ET + (size_t)(bn+lr)*K + k0+lc);
            Bs[lc+0][lr]=bv.x; Bs[lc+1][lr]=bv.y; Bs[lc+2][lr]=bv.z; Bs[lc+3][lr]=bv.w;
            __syncthreads();
            #pragma unroll
            for (int k=0;k<16;++k){
                float a[4], b[4];
                #pragma unroll
                for (int i=0;i<4;++i) a[i]=As[k][(ty<<2)+i];
                #pragma unroll
                for (int j=0;j<4;++j) b[j]=Bs[k][(tx<<2)+j];
                #pragma unroll
                for (int i=0;i<4;++i)
                    #pragma unroll
                    for (int j=0;j<4;++j)
                        acc[i][j] += a[i]*b[j];
            }
            __syncthreads();
        }
        #pragma unroll
        for (int i=0;i<4;++i)
            #pragma unroll
            for (int j=0;j<4;++j)
                Sc[(ty<<2)+i][(tx<<2)+j] = acc[i][j];
        __syncthreads();
        #pragma unroll
        for (int i=0;i<16;++i){
            float v = Sc[r][(q<<4)+i];
            if (v > tv[5]){
                int c = bn + (q<<4) + i;
                tv[5]=v; ti[5]=c;
                #pragma unroll
                for (int u=5;u>0;--u){
                    if (tv[u] > tv[u-1]){
                        float tf=tv[u]; tv[u]=tv[u-1]; tv[u-1]=tf;
                        int tg=ti[u]; ti[u]=ti[u-1]; ti[u-1]=tg;
                    }
                }
            }
        }
        __syncthreads();
    }
    // merge 4 per-row partial top6 -> top6 for this column quarter
    float* Mv = &Sc[0][0];               // 1536 floats
    int*   Mi = (int*)(&Sc[0][0]) + 1536;
    __syncthreads();
    #pragma unroll
    for (int k=0;k<6;++k){
        Mv[r*24 + q*6 + k] = tv[k];
        Mi[r*24 + q*6 + k] = ti[k];
    }
    __syncthreads();
    if (tid < 64){
        int row = bm + tid;
        float* mv = Mv + tid*24;
        int*   mi = Mi + tid*24;
        unsigned used = 0;
        for (int k=0;k<6;++k){
            float bvv = -INFINITY; int bc = 0;
            for (int c=0;c<24;++c){
                if (!((used>>c)&1u) && mv[c] > bvv){ bvv=mv[c]; bc=c; }
            }
            used |= 1u<<bc;
            VALS[(size_t)row*24 + blockIdx.y*6 + k] = bvv;
            IDX[(size_t)row*24 + blockIdx.y*6 + k]  = mi[bc];
        }
    }
}

// ---------------- KNN aggregation: p-softmax, gate, kp-softmax, e_Nh ----------------
__global__ __launch_bounds__(256) void knn_agg(
    const float* __restrict__ EH, const float* __restrict__ ET,
    const float* __restrict__ VALS, const int* __restrict__ IDX,
    float* __restrict__ ENH)
{
    int wave = threadIdx.x >> 6, lane = threadIdx.x & 63;
    int row = (blockIdx.x<<2) + wave;
    // merge 4 quarter-top6 lists -> global top6 (quarters are in column order,
    // scan keeps lowest index on ties, matching np.top_k)
    float v24[24]; int i24[24];
    #pragma unroll
    for (int c=0;c<24;++c){ v24[c]=VALS[(size_t)row*24+c]; i24[c]=IDX[(size_t)row*24+c]; }
    float v[6]; int id[6];
    unsigned used=0;
    #pragma unroll
    for (int k=0;k<6;++k){
        float bv=-INFINITY; int bc=0;
        #pragma unroll
        for (int c=0;c<24;++c) if(!((used>>c)&1u) && v24[c]>bv){ bv=v24[c]; bc=c; }
        used|=1u<<bc; v[k]=bv; id[k]=i24[bc];
    }
    // p = softmax(vals)
    float mx=v[0];
    #pragma unroll
    for (int k=1;k<6;++k) mx=fmaxf(mx,v[k]);
    float p[6], se=0.f;
    #pragma unroll
    for (int k=0;k<6;++k){ p[k]=expf(v[k]-mx); se+=p[k]; }
    float inv=1.f/se;
    #pragma unroll
    for (int k=0;k<6;++k) p[k]*=inv;

    const float* ehr = EH + (size_t)row*512;
    float e[8];
    #pragma unroll
    for (int j=0;j<8;++j) e[j]=ehr[lane + (j<<6)];
    float nb[6][8], sn[6], sg[6];
    #pragma unroll
    for (int k=0;k<6;++k){
        const float* nr = ET + (size_t)id[k]*512;
        float s_n=0.f, s_g=0.f;
        #pragma unroll
        for (int j=0;j<8;++j){
            float nv = nr[lane+(j<<6)];
            nb[k][j]=nv;
            s_n += nv;
            float ehr_v = p[k]*nv + (1.f-p[k])*e[j];
            s_g += tanhf(e[j] + ehr_v);
        }
        #pragma unroll
        for (int o=1;o<64;o<<=1){ s_n += __shfl_xor(s_n,o,64); s_g += __shfl_xor(s_g,o,64); }
        sn[k]=s_n; sg[k]=s_g;
    }
    float ka[6];
    #pragma unroll
    for (int k=0;k<6;++k) ka[k]=sn[k]*sg[k];
    float km=ka[0];
    #pragma unroll
    for (int k=1;k<6;++k) km=fmaxf(km,ka[k]);
    float kp[6], ks=0.f;
    #pragma unroll
    for (int k=0;k<6;++k){ kp[k]=expf(ka[k]-km); ks+=kp[k]; }
    float kinv=1.f/ks;
    #pragma unroll
    for (int k=0;k<6;++k) kp[k]*=kinv;
    float o8[8]={0,0,0,0,0,0,0,0};
    #pragma unroll
    for (int k=0;k<6;++k)
        #pragma unroll
        for (int j=0;j<8;++j) o8[j] += kp[k]*nb[k][j];
    #pragma unroll
    for (int j=0;j<8;++j) ENH[(size_t)row*512 + lane + (j<<6)] = o8[j];
}

// ---------------- fused dual GEMM: e_h2 = leaky((eh+enh)W1^T+b1)+leaky((eh*enh)W2^T+b2) ----------------
__global__ __launch_bounds__(256) void lin12(
    const float* __restrict__ EHM, const float* __restrict__ ENH,
    const float* __restrict__ W1, const float* __restrict__ B1v,
    const float* __restrict__ W2, const float* __restrict__ B2v,
    float* __restrict__ OUTF)
{
    const int K = 512, N = 512;
    __shared__ float Aa[16][68], Am[16][68], S1[16][68], S2[16][68];
    int tid=threadIdx.x, tx=tid&15, ty=tid>>4;
    int bm=blockIdx.y<<6, bn=blockIdx.x<<6;
    int lr=tid>>2, lc=(tid&3)<<2;
    float acc1[4][4]={}, acc2[4][4]={};
    for (int k0=0;k0<K;k0+=16){
        float4 ev = *(const float4*)(EHM + (size_t)(bm+lr)*K + k0+lc);
        float4 nv = *(const float4*)(ENH + (size_t)(bm+lr)*K + k0+lc);
        Aa[lc+0][lr]=ev.x+nv.x; Aa[lc+1][lr]=ev.y+nv.y; Aa[lc+2][lr]=ev.z+nv.z; Aa[lc+3][lr]=ev.w+nv.w;
        Am[lc+0][lr]=ev.x*nv.x; Am[lc+1][lr]=ev.y*nv.y; Am[lc+2][lr]=ev.z*nv.z; Am[lc+3][lr]=ev.w*nv.w;
        float4 w1v = *(const float4*)(W1 + (size_t)(bn+lr)*K + k0+lc);
        S1[lc+0][lr]=w1v.x; S1[lc+1][lr]=w1v.y; S1[lc+2][lr]=w1v.z; S1[lc+3][lr]=w1v.w;
        float4 w2v = *(const float4*)(W2 + (size_t)(bn+lr)*K + k0+lc);
        S2[lc+0][lr]=w2v.x; S2[lc+1][lr]=w2v.y; S2[lc+2][lr]=w2v.z; S2[lc+3][lr]=w2v.w;
        __syncthreads();
        #pragma unroll
        for (int k=0;k<16;++k){
            float aa[4], am[4], b1[4], b2[4];
            #pragma unroll
            for (int i=0;i<4;++i){ aa[i]=Aa[k][(ty<<2)+i]; am[i]=Am[k][(ty<<2)+i]; }
            #pragma unroll
            for (int j=0;j<4;++j){ b1[j]=S1[k][(tx<<2)+j]; b2[j]=S2[k][(tx<<2)+j]; }
            #pragma unroll
            for (int i=0;i<4;++i)
                #pragma unroll
                for (int j=0;j<4;++j){
                    acc1[i][j] += aa[i]*b1[j];
                    acc2[i][j] += am[i]*b2[j];
                }
        }
        __syncthreads();
    }
    #pragma unroll
    for (int i=0;i<4;++i){
        int rr = bm + (ty<<2) + i;
        #pragma unroll
        for (int j=0;j<4;++j){
            int cc = bn + (tx<<2) + j;
            float s1 = leakyf(acc1[i][j] + B1v[cc]);
            float s2 = leakyf(acc2[i][j] + B2v[cc]);
            OUTF[(size_t)rr*N + cc] = s1 + s2;
        }
    }
}

// ---------------- attention readout ----------------
__global__ __launch_bounds__(256) void att_g(
    const float* __restrict__ HM, const float* __restrict__ W2,
    const float* __restrict__ B2, float* __restrict__ G)
{
    int wave=threadIdx.x>>6, lane=threadIdx.x&63;
    int row=(blockIdx.x<<2)+wave;
    const float* hr = HM + (size_t)row*256;
    float s=0.f;
    #pragma unroll
    for (int j=0;j<4;++j) s += hr[lane+(j<<6)] * W2[lane+(j<<6)];
    #pragma unroll
    for (int o=1;o<64;o<<=1) s += __shfl_xor(s,o,64);
    if (lane==0) G[row] = s + B2[0];
}

__global__ __launch_bounds__(1024) void softg(float* __restrict__ G)
{
    __shared__ float red[1024];
    __shared__ float MS[2];
    int t=threadIdx.x;
    float m=-INFINITY;
    for (int i=t;i<8192;i+=1024) m=fmaxf(m,G[i]);
    red[t]=m; __syncthreads();
    for (int o=512;o>0;o>>=1){ if(t<o) red[t]=fmaxf(red[t],red[t+o]); __syncthreads(); }
    if (t==0) MS[0]=red[0];
    __syncthreads();
    float M=MS[0], s=0.f;
    for (int i=t;i<8192;i+=1024) s += expf(G[i]-M);
    red[t]=s; __syncthreads();
    for (int o=512;o>0;o>>=1){ if(t<o) red[t]+=red[t+o]; __syncthreads(); }
    if (t==0) MS[1]=red[0];
    __syncthreads();
    float inv=1.f/MS[1];
    for (int i=t;i<8192;i+=1024) G[i] = expf(G[i]-M)*inv;
}

__global__ __launch_bounds__(256) void eg_kernel(
    const float* __restrict__ A, const float* __restrict__ X, float* __restrict__ OUT)
{
    __shared__ float red[256];
    int d = blockIdx.x, t = threadIdx.x;
    float s=0.f;
    for (int i=t;i<8192;i+=256) s += A[i]*X[(size_t)i*512 + d];
    red[t]=s; __syncthreads();
    for (int o=128;o>0;o>>=1){ if(t<o) red[t]+=red[t+o]; __syncthreads(); }
    if (t==0) OUT[d] = red[0];
}

// ---------------- launch ----------------
extern "C" void kernel_launch(void* const* d_in, const int* in_sizes, int n_in,
                              void* d_out, int out_size, void* d_ws, size_t ws_size,
                              hipStream_t stream)
{
    (void)n_in; (void)out_size; (void)ws_size;
    static const int ss[6] = {89,334,534,471,1510,482};

    // Layout detection (R3 evidence: dict order is the real one; keep both).
    bool sig_order = (in_sizes[12] == 1536);

    OmicArgs oa;
    const float *sb1, *sw2, *sb2, *xpath;
    if (sig_order) {
        for (int i=0;i<6;++i){ oa.x[i]=(const float*)d_in[i]; oa.w1[i]=(const float*)d_in[6+i]; oa.s[i]=ss[i]; }
        sb1   = (const float*)d_in[12];
        sw2   = (const float*)d_in[13];
        sb2   = (const float*)d_in[14];
        xpath = (const float*)d_in[15];
    } else {
        for (int i=0;i<6;++i){ oa.x[i]=(const float*)d_in[2*i]; oa.w1[i]=(const float*)d_in[2*i+1]; oa.s[i]=ss[i]; }
        xpath = (const float*)d_in[12];
        sb1   = (const float*)d_in[13];
        sw2   = (const float*)d_in[14];
        sb2   = (const float*)d_in[15];
    }
    const float* fc1w = (const float*)d_in[16];
    const float* fc1b = (const float*)d_in[17];
    const float* whw  = (const float*)d_in[18];
    const float* whb  = (const float*)d_in[19];
    const float* wtw  = (const float*)d_in[20];
    const float* wtb  = (const float*)d_in[21];
    const float* l1w  = (const float*)d_in[22];
    const float* l1b  = (const float*)d_in[23];
    const float* l2w  = (const float*)d_in[24];
    const float* l2b  = (const float*)d_in[25];
    const float* aw1  = (const float*)d_in[26];
    const float* ab1  = (const float*)d_in[27];
    const float* aw2  = (const float*)d_in[28];
    const float* ab2  = (const float*)d_in[29];

    float* out = (float*)d_out;            // fp32 outputs: e_omic | e_h2 | e_g
    float* eh2 = out + 1536;               // 8192*512
    float* egp = out + 1536 + 4194304;     // 512

    float* ws   = (float*)d_ws;            // ~52 MB of fp32 scratch
    float* hbuf = ws;                      // 8192*512 (h; reused as enh)
    float* ehb  = hbuf + 4194304;          // 8192*512
    float* etb  = ehb + 4194304;           // 8192*512 (reused as hm 8192*256)
    float* mcol = etb + 4194304;           // 512
    float* gbuf = mcol + 512;              // 8192
    float* vals = gbuf + 8192;             // 8192*24
    int*   idxb = (int*)(vals + 196608);   // 8192*24
    float* enh  = hbuf;
    float* hm   = etb;

    omic_kernel<<<6,256,0,stream>>>(oa, sb1, sw2, sb2, out);

    gemm_awt<1><<<dim3(8,128),256,0,stream>>>(xpath, fc1w, fc1b, hbuf, 8192,512,384);
    colmean<<<512,256,0,stream>>>(hbuf, mcol);
    hupd<<<16384,256,0,stream>>>(hbuf, mcol);
    gemm_awt<0><<<dim3(8,128),256,0,stream>>>(hbuf, whw, whb, ehb, 8192,512,512);
    gemm_awt<0><<<dim3(8,128),256,0,stream>>>(hbuf, wtw, wtb, etb, 8192,512,512);
    logits_topk<<<dim3(128,4),256,0,stream>>>(ehb, etb, vals, idxb);
    knn_agg<<<2048,256,0,stream>>>(ehb, etb, vals, idxb, enh);
    lin12<<<dim3(8,128),256,0,stream>>>(ehb, enh, l1w, l1b, l2w, l2b, eh2);
    gemm_awt<1><<<dim3(4,128),256,0,stream>>>(eh2, aw1, ab1, hm, 8192,256,512);
    att_g<<<2048,256,0,stream>>>(hm, aw2, ab2, gbuf);
    softg<<<1,1024,0,stream>>>(gbuf);
    eg_kernel<<<512,256,0,stream>>>(gbuf, eh2, egp);
}

// Round 5
// 1394.869 us; speedup vs baseline: 1.3603x; 1.3603x over previous
//
#include <hip/hip_runtime.h>
#include <math.h>

typedef unsigned short u16;
typedef unsigned int u32;
typedef __attribute__((ext_vector_type(8))) short s8v;   // 8 x bf16 (4 VGPRs)
typedef __attribute__((ext_vector_type(4))) float f4v;   // MFMA acc

__device__ __forceinline__ float b2f(u16 u){ union{u32 i; float f;} v; v.i=((u32)u)<<16; return v.f; }
__device__ __forceinline__ u16 f2b(float f){ union{float f; u32 i;} v; v.f=f; u32 x=v.i; return (u16)((x + 0x7fffu + ((x>>16)&1u)) >> 16); }
__device__ __forceinline__ float leakyf(float x){ return x>=0.f? x : 0.01f*x; }

#define MFMA16(a,b,c) __builtin_amdgcn_mfma_f32_16x16x32_bf16(a,b,c,0,0,0)

// ---------------- omic SNN branches ----------------
struct OmicArgs {
    const float* x[6];
    const float* w1[6];
    int s[6];
};

__global__ __launch_bounds__(256) void omic_kernel(OmicArgs oa,
        const float* __restrict__ sb1, const float* __restrict__ sw2,
        const float* __restrict__ sb2, float* __restrict__ out)
{
    int br = blockIdx.x;
    int t = threadIdx.x;
    int s = oa.s[br];
    __shared__ float xs[1536];
    __shared__ float h1[256];
    const float* x = oa.x[br];
    for (int i=t;i<s;i+=256) xs[i] = x[i];
    __syncthreads();
    const float* w1r = oa.w1[br] + (size_t)t * s;
    float a = sb1[br*256+t];
    for (int i=0;i<s;++i) a += xs[i]*w1r[i];
    a = a>0.f ? a : expm1f(a);
    h1[t] = a;
    __syncthreads();
    const float* w2r = sw2 + (size_t)br*65536 + (size_t)t*256;
    float a2 = sb2[br*256+t];
    #pragma unroll 4
    for (int i=0;i<256;++i) a2 += h1[i]*w2r[i];
    a2 = a2>0.f ? a2 : expm1f(a2);
    out[br*256+t] = a2;
}

// ---------------- generic fp32 GEMM: C = act(A[M,K] @ W[N,K]^T + b) ----------------
template<int ACT>
__global__ __launch_bounds__(256) void gemm_awt(
    const float* __restrict__ A, const float* __restrict__ W,
    const float* __restrict__ bias, float* __restrict__ C,
    int M, int N, int K)
{
    __shared__ float As[16][68];
    __shared__ float Bs[16][68];
    int tid = threadIdx.x;
    int tx = tid & 15, ty = tid >> 4;
    int bm = blockIdx.y << 6, bn = blockIdx.x << 6;
    int lr = tid >> 2, lc = (tid & 3) << 2;
    float acc[4][4] = {};
    for (int k0=0;k0<K;k0+=16){
        float4 av = *(const float4*)(A + (size_t)(bm+lr)*K + k0 + lc);
        As[lc+0][lr]=av.x; As[lc+1][lr]=av.y; As[lc+2][lr]=av.z; As[lc+3][lr]=av.w;
        float4 wv = *(const float4*)(W + (size_t)(bn+lr)*K + k0 + lc);
        Bs[lc+0][lr]=wv.x; Bs[lc+1][lr]=wv.y; Bs[lc+2][lr]=wv.z; Bs[lc+3][lr]=wv.w;
        __syncthreads();
        #pragma unroll
        for (int k=0;k<16;++k){
            float a[4], b[4];
            #pragma unroll
            for (int i=0;i<4;++i) a[i]=As[k][(ty<<2)+i];
            #pragma unroll
            for (int j=0;j<4;++j) b[j]=Bs[k][(tx<<2)+j];
            #pragma unroll
            for (int i=0;i<4;++i)
                #pragma unroll
                for (int j=0;j<4;++j)
                    acc[i][j] += a[i]*b[j];
        }
        __syncthreads();
    }
    #pragma unroll
    for (int i=0;i<4;++i){
        int rr = bm + (ty<<2) + i;
        #pragma unroll
        for (int j=0;j<4;++j){
            int cc = bn + (tx<<2) + j;
            float vv = acc[i][j] + bias[cc];
            if (ACT==1) vv = leakyf(vv);
            C[(size_t)rr*N + cc] = vv;
        }
    }
}

// ---------------- fp32 GEMM with split-bf16 (hi/lo) output, N=K=512 ----------------
__global__ __launch_bounds__(256) void gemm_awt_split(
    const float* __restrict__ A, const float* __restrict__ W,
    const float* __restrict__ bias, u16* __restrict__ OH, u16* __restrict__ OL)
{
    const int K = 512, N = 512;
    __shared__ float As[16][68];
    __shared__ float Bs[16][68];
    int tid = threadIdx.x;
    int tx = tid & 15, ty = tid >> 4;
    int bm = blockIdx.y << 6, bn = blockIdx.x << 6;
    int lr = tid >> 2, lc = (tid & 3) << 2;
    float acc[4][4] = {};
    for (int k0=0;k0<K;k0+=16){
        float4 av = *(const float4*)(A + (size_t)(bm+lr)*K + k0 + lc);
        As[lc+0][lr]=av.x; As[lc+1][lr]=av.y; As[lc+2][lr]=av.z; As[lc+3][lr]=av.w;
        float4 wv = *(const float4*)(W + (size_t)(bn+lr)*K + k0 + lc);
        Bs[lc+0][lr]=wv.x; Bs[lc+1][lr]=wv.y; Bs[lc+2][lr]=wv.z; Bs[lc+3][lr]=wv.w;
        __syncthreads();
        #pragma unroll
        for (int k=0;k<16;++k){
            float a[4], b[4];
            #pragma unroll
            for (int i=0;i<4;++i) a[i]=As[k][(ty<<2)+i];
            #pragma unroll
            for (int j=0;j<4;++j) b[j]=Bs[k][(tx<<2)+j];
            #pragma unroll
            for (int i=0;i<4;++i)
                #pragma unroll
                for (int j=0;j<4;++j)
                    acc[i][j] += a[i]*b[j];
        }
        __syncthreads();
    }
    #pragma unroll
    for (int i=0;i<4;++i){
        int rr = bm + (ty<<2) + i;
        #pragma unroll
        for (int j=0;j<4;++j){
            int cc = bn + (tx<<2) + j;
            float vv = acc[i][j] + bias[cc];
            u16 hi = f2b(vv);
            u16 lo = f2b(vv - b2f(hi));
            OH[(size_t)rr*N + cc] = hi;
            OL[(size_t)rr*N + cc] = lo;
        }
    }
}

// ---------------- column mean + h update ----------------
__global__ __launch_bounds__(256) void colmean(const float* __restrict__ H, float* __restrict__ Mc)
{
    __shared__ float red[256];
    int c=blockIdx.x, t=threadIdx.x;
    float s=0;
    for (int i=t;i<8192;i+=256) s += H[(size_t)i*512 + c];
    red[t]=s; __syncthreads();
    for (int o=128;o>0;o>>=1){ if(t<o) red[t]+=red[t+o]; __syncthreads(); }
    if (t==0) Mc[c] = red[0] * (1.0f/8192.0f);
}

__global__ __launch_bounds__(256) void hupd(float* __restrict__ H, const float* __restrict__ Mc)
{
    int i = blockIdx.x*256 + threadIdx.x;
    H[i] = (H[i] + Mc[i & 511]) * 0.5f;
}

// ---------------- MFMA split-bf16 logits GEMM + fused top-6 (per column-eighth) ----------------
// Block tile: 128 rows x 64 cols per iteration, 16 col-tiles (1024-col range).
// Each of 4 waves: 32 rows x 64 cols = 2x4 [16x16] MFMA tiles, 3 split-MFMAs per k32.
struct TileMem { u16 Ah[128*72]; u16 Al[128*72]; u16 Bh[64*72]; u16 Bl[64*72]; }; // 55296 B
struct EpiMem  { float Sc[128*65]; float Mv[128*12]; int Mi[128*12]; };           // 45568 B
union SMemU { TileMem t; EpiMem e; };

__global__ __launch_bounds__(256,2) void logits_topk_mfma(
    const u16* __restrict__ EHH, const u16* __restrict__ EHL,
    const u16* __restrict__ ETH, const u16* __restrict__ ETL,
    float* __restrict__ VALS, int* __restrict__ IDX)
{
    const float scale = 0.04419417382415922f; // 512^-0.5
    __shared__ SMemU sm;
    int tid = threadIdx.x;
    int bm = blockIdx.x << 7;       // 128 rows
    int base = blockIdx.y << 10;    // 1024 cols
    int w = tid >> 6, lane = tid & 63;
    int lrow = lane & 15, quad = lane >> 4;
    int srow = tid >> 3;            // 0..31 staging row group
    int scol = (tid & 7) << 3;      // 0..56 staging col (u16 units)
    int r = tid >> 1, q = tid & 1;  // topk: row 0..127, col half

    float tv[6]; int ti[6];
    #pragma unroll
    for (int k=0;k<6;++k){ tv[k]=-INFINITY; ti[k]=0; }

    for (int bn = base; bn < base + 1024; bn += 64){
        f4v acc[2][4];
        #pragma unroll
        for (int mi=0;mi<2;++mi)
            #pragma unroll
            for (int t=0;t<4;++t){ acc[mi][t][0]=0.f; acc[mi][t][1]=0.f; acc[mi][t][2]=0.f; acc[mi][t][3]=0.f; }

        for (int k0 = 0; k0 < 512; k0 += 64){
            __syncthreads();
            #pragma unroll
            for (int j = 0; j < 4; ++j){
                int rr = srow + (j << 5);
                size_t g = (size_t)(bm + rr) * 512 + k0 + scol;
                *(uint4*)&sm.t.Ah[rr*72 + scol] = *(const uint4*)(EHH + g);
                *(uint4*)&sm.t.Al[rr*72 + scol] = *(const uint4*)(EHL + g);
            }
            #pragma unroll
            for (int j = 0; j < 2; ++j){
                int rr = srow + (j << 5);
                size_t g = (size_t)(bn + rr) * 512 + k0 + scol;
                *(uint4*)&sm.t.Bh[rr*72 + scol] = *(const uint4*)(ETH + g);
                *(uint4*)&sm.t.Bl[rr*72 + scol] = *(const uint4*)(ETL + g);
            }
            __syncthreads();
            #pragma unroll
            for (int kk = 0; kk < 64; kk += 32){
                int ko = kk + (quad << 3);
                s8v a0h = *(const s8v*)&sm.t.Ah[((w<<5) + lrow)*72 + ko];
                s8v a0l = *(const s8v*)&sm.t.Al[((w<<5) + lrow)*72 + ko];
                s8v a1h = *(const s8v*)&sm.t.Ah[((w<<5) + 16 + lrow)*72 + ko];
                s8v a1l = *(const s8v*)&sm.t.Al[((w<<5) + 16 + lrow)*72 + ko];
                #pragma unroll
                for (int t = 0; t < 4; ++t){
                    s8v bh = *(const s8v*)&sm.t.Bh[((t<<4) + lrow)*72 + ko];
                    s8v bl = *(const s8v*)&sm.t.Bl[((t<<4) + lrow)*72 + ko];
                    acc[0][t] = MFMA16(a0h, bh, acc[0][t]);
                    acc[0][t] = MFMA16(a0h, bl, acc[0][t]);
                    acc[0][t] = MFMA16(a0l, bh, acc[0][t]);
                    acc[1][t] = MFMA16(a1h, bh, acc[1][t]);
                    acc[1][t] = MFMA16(a1h, bl, acc[1][t]);
                    acc[1][t] = MFMA16(a1l, bh, acc[1][t]);
                }
            }
        }
        __syncthreads();
        // D mapping: col = lane&15, row = (lane>>4)*4 + reg
        #pragma unroll
        for (int mi=0;mi<2;++mi)
            #pragma unroll
            for (int t=0;t<4;++t)
                #pragma unroll
                for (int i=0;i<4;++i){
                    int rr = (w<<5) + (mi<<4) + (quad<<2) + i;
                    sm.e.Sc[rr*65 + (t<<4) + lrow] = acc[mi][t][i] * scale;
                }
        __syncthreads();
        const float* srcrow = &sm.e.Sc[r*65 + (q<<5)];
        int cbase = bn + (q<<5);
        #pragma unroll
        for (int i=0;i<32;++i){
            float v = srcrow[i];
            if (v > tv[5]){
                tv[5]=v; ti[5]=cbase+i;
                #pragma unroll
                for (int u=5;u>0;--u){
                    if (tv[u] > tv[u-1]){
                        float tf=tv[u]; tv[u]=tv[u-1]; tv[u-1]=tf;
                        int tg=ti[u]; ti[u]=ti[u-1]; ti[u-1]=tg;
                    }
                }
            }
        }
        __syncthreads();
    }
    // merge 2 half-lists per row -> per-block top6
    #pragma unroll
    for (int k=0;k<6;++k){ sm.e.Mv[r*12 + q*6 + k] = tv[k]; sm.e.Mi[r*12 + q*6 + k] = ti[k]; }
    __syncthreads();
    if (tid < 128){
        int row = bm + tid;
        float* mv = &sm.e.Mv[tid*12];
        int*   mi = &sm.e.Mi[tid*12];
        unsigned used = 0;
        for (int k=0;k<6;++k){
            float bv=-INFINITY; int bc=0;
            for (int c=0;c<12;++c) if (!((used>>c)&1u) && mv[c] > bv){ bv=mv[c]; bc=c; }
            used |= 1u<<bc;
            VALS[(size_t)row*48 + blockIdx.y*6 + k] = bv;
            IDX [(size_t)row*48 + blockIdx.y*6 + k] = mi[bc];
        }
    }
}

// ---------------- KNN aggregation: merge 8 lists, p-softmax, gate, kp-softmax, e_Nh ----------------
__global__ __launch_bounds__(256) void knn_agg(
    const u16* __restrict__ EHH, const u16* __restrict__ EHL,
    const u16* __restrict__ ETH, const u16* __restrict__ ETL,
    const float* __restrict__ VALS, const int* __restrict__ IDX,
    float* __restrict__ ENH)
{
    int wave = threadIdx.x >> 6, lane = threadIdx.x & 63;
    int row = (blockIdx.x<<2) + wave;
    float v48[48]; int i48[48];
    #pragma unroll
    for (int c=0;c<48;++c){ v48[c]=VALS[(size_t)row*48+c]; i48[c]=IDX[(size_t)row*48+c]; }
    float v[6]; int id[6];
    #pragma unroll
    for (int k=0;k<6;++k){
        float bv=-INFINITY; int bc=0;
        #pragma unroll
        for (int c=0;c<48;++c) if (v48[c]>bv){ bv=v48[c]; bc=c; }
        v[k]=bv; id[k]=i48[bc]; v48[bc]=-INFINITY;
    }
    float mx=v[0];
    #pragma unroll
    for (int k=1;k<6;++k) mx=fmaxf(mx,v[k]);
    float p[6], se=0.f;
    #pragma unroll
    for (int k=0;k<6;++k){ p[k]=expf(v[k]-mx); se+=p[k]; }
    float inv=1.f/se;
    #pragma unroll
    for (int k=0;k<6;++k) p[k]*=inv;

    size_t ro = (size_t)row*512;
    float e[8];
    #pragma unroll
    for (int j=0;j<8;++j){ int o = lane + (j<<6); e[j]=b2f(EHH[ro+o])+b2f(EHL[ro+o]); }
    float nb[6][8], sn[6], sg[6];
    #pragma unroll
    for (int k=0;k<6;++k){
        size_t no = (size_t)id[k]*512;
        float s_n=0.f, s_g=0.f;
        #pragma unroll
        for (int j=0;j<8;++j){
            int o = lane + (j<<6);
            float nv = b2f(ETH[no+o])+b2f(ETL[no+o]);
            nb[k][j]=nv;
            s_n += nv;
            float ehr_v = p[k]*nv + (1.f-p[k])*e[j];
            s_g += tanhf(e[j] + ehr_v);
        }
        #pragma unroll
        for (int o=1;o<64;o<<=1){ s_n += __shfl_xor(s_n,o,64); s_g += __shfl_xor(s_g,o,64); }
        sn[k]=s_n; sg[k]=s_g;
    }
    float ka[6];
    #pragma unroll
    for (int k=0;k<6;++k) ka[k]=sn[k]*sg[k];
    float km=ka[0];
    #pragma unroll
    for (int k=1;k<6;++k) km=fmaxf(km,ka[k]);
    float kp[6], ks=0.f;
    #pragma unroll
    for (int k=0;k<6;++k){ kp[k]=expf(ka[k]-km); ks+=kp[k]; }
    float kinv=1.f/ks;
    #pragma unroll
    for (int k=0;k<6;++k) kp[k]*=kinv;
    float o8[8]={0,0,0,0,0,0,0,0};
    #pragma unroll
    for (int k=0;k<6;++k)
        #pragma unroll
        for (int j=0;j<8;++j) o8[j] += kp[k]*nb[k][j];
    #pragma unroll
    for (int j=0;j<8;++j) ENH[ro + lane + (j<<6)] = o8[j];
}

// ---------------- fused dual GEMM: e_h2 = leaky((eh+enh)W1^T+b1)+leaky((eh*enh)W2^T+b2) ----------------
__global__ __launch_bounds__(256) void lin12(
    const u16* __restrict__ EHH, const u16* __restrict__ EHL,
    const float* __restrict__ ENH,
    const float* __restrict__ W1, const float* __restrict__ B1v,
    const float* __restrict__ W2, const float* __restrict__ B2v,
    float* __restrict__ OUTF)
{
    const int K = 512, N = 512;
    __shared__ float Aa[16][68], Am[16][68], S1[16][68], S2[16][68];
    int tid=threadIdx.x, tx=tid&15, ty=tid>>4;
    int bm=blockIdx.y<<6, bn=blockIdx.x<<6;
    int lr=tid>>2, lc=(tid&3)<<2;
    float acc1[4][4]={}, acc2[4][4]={};
    for (int k0=0;k0<K;k0+=16){
        size_t aoff = (size_t)(bm+lr)*K + k0+lc;
        ushort4 hv = *(const ushort4*)(EHH + aoff);
        ushort4 lv = *(const ushort4*)(EHL + aoff);
        float ex = b2f(hv.x)+b2f(lv.x), ey = b2f(hv.y)+b2f(lv.y);
        float ez = b2f(hv.z)+b2f(lv.z), ew = b2f(hv.w)+b2f(lv.w);
        float4 nv = *(const float4*)(ENH + aoff);
        Aa[lc+0][lr]=ex+nv.x; Aa[lc+1][lr]=ey+nv.y; Aa[lc+2][lr]=ez+nv.z; Aa[lc+3][lr]=ew+nv.w;
        Am[lc+0][lr]=ex*nv.x; Am[lc+1][lr]=ey*nv.y; Am[lc+2][lr]=ez*nv.z; Am[lc+3][lr]=ew*nv.w;
        float4 w1v = *(const float4*)(W1 + (size_t)(bn+lr)*K + k0+lc);
        S1[lc+0][lr]=w1v.x; S1[lc+1][lr]=w1v.y; S1[lc+2][lr]=w1v.z; S1[lc+3][lr]=w1v.w;
        float4 w2v = *(const float4*)(W2 + (size_t)(bn+lr)*K + k0+lc);
        S2[lc+0][lr]=w2v.x; S2[lc+1][lr]=w2v.y; S2[lc+2][lr]=w2v.z; S2[lc+3][lr]=w2v.w;
        __syncthreads();
        #pragma unroll
        for (int k=0;k<16;++k){
            float aa[4], am[4], b1[4], b2[4];
            #pragma unroll
            for (int i=0;i<4;++i){ aa[i]=Aa[k][(ty<<2)+i]; am[i]=Am[k][(ty<<2)+i]; }
            #pragma unroll
            for (int j=0;j<4;++j){ b1[j]=S1[k][(tx<<2)+j]; b2[j]=S2[k][(tx<<2)+j]; }
            #pragma unroll
            for (int i=0;i<4;++i)
                #pragma unroll
                for (int j=0;j<4;++j){
                    acc1[i][j] += aa[i]*b1[j];
                    acc2[i][j] += am[i]*b2[j];
                }
        }
        __syncthreads();
    }
    #pragma unroll
    for (int i=0;i<4;++i){
        int rr = bm + (ty<<2) + i;
        #pragma unroll
        for (int j=0;j<4;++j){
            int cc = bn + (tx<<2) + j;
            float s1 = leakyf(acc1[i][j] + B1v[cc]);
            float s2 = leakyf(acc2[i][j] + B2v[cc]);
            OUTF[(size_t)rr*N + cc] = s1 + s2;
        }
    }
}

// ---------------- attention readout ----------------
__global__ __launch_bounds__(256) void att_g(
    const float* __restrict__ HM, const float* __restrict__ W2,
    const float* __restrict__ B2, float* __restrict__ G)
{
    int wave=threadIdx.x>>6, lane=threadIdx.x&63;
    int row=(blockIdx.x<<2)+wave;
    const float* hr = HM + (size_t)row*256;
    float s=0.f;
    #pragma unroll
    for (int j=0;j<4;++j) s += hr[lane+(j<<6)] * W2[lane+(j<<6)];
    #pragma unroll
    for (int o=1;o<64;o<<=1) s += __shfl_xor(s,o,64);
    if (lane==0) G[row] = s + B2[0];
}

__global__ __launch_bounds__(1024) void softg(float* __restrict__ G)
{
    __shared__ float red[1024];
    __shared__ float MS[2];
    int t=threadIdx.x;
    float m=-INFINITY;
    for (int i=t;i<8192;i+=1024) m=fmaxf(m,G[i]);
    red[t]=m; __syncthreads();
    for (int o=512;o>0;o>>=1){ if(t<o) red[t]=fmaxf(red[t],red[t+o]); __syncthreads(); }
    if (t==0) MS[0]=red[0];
    __syncthreads();
    float M=MS[0], s=0.f;
    for (int i=t;i<8192;i+=1024) s += expf(G[i]-M);
    red[t]=s; __syncthreads();
    for (int o=512;o>0;o>>=1){ if(t<o) red[t]+=red[t+o]; __syncthreads(); }
    if (t==0) MS[1]=red[0];
    __syncthreads();
    float inv=1.f/MS[1];
    for (int i=t;i<8192;i+=1024) G[i] = expf(G[i]-M)*inv;
}

__global__ __launch_bounds__(256) void eg_kernel(
    const float* __restrict__ A, const float* __restrict__ X, float* __restrict__ OUT)
{
    __shared__ float red[256];
    int d = blockIdx.x, t = threadIdx.x;
    float s=0.f;
    for (int i=t;i<8192;i+=256) s += A[i]*X[(size_t)i*512 + d];
    red[t]=s; __syncthreads();
    for (int o=128;o>0;o>>=1){ if(t<o) red[t]+=red[t+o]; __syncthreads(); }
    if (t==0) OUT[d] = red[0];
}

// ---------------- launch ----------------
extern "C" void kernel_launch(void* const* d_in, const int* in_sizes, int n_in,
                              void* d_out, int out_size, void* d_ws, size_t ws_size,
                              hipStream_t stream)
{
    (void)n_in; (void)out_size; (void)ws_size;
    static const int ss[6] = {89,334,534,471,1510,482};

    bool sig_order = (in_sizes[12] == 1536);
    OmicArgs oa;
    const float *sb1, *sw2, *sb2, *xpath;
    if (sig_order) {
        for (int i=0;i<6;++i){ oa.x[i]=(const float*)d_in[i]; oa.w1[i]=(const float*)d_in[6+i]; oa.s[i]=ss[i]; }
        sb1   = (const float*)d_in[12];
        sw2   = (const float*)d_in[13];
        sb2   = (const float*)d_in[14];
        xpath = (const float*)d_in[15];
    } else {
        for (int i=0;i<6;++i){ oa.x[i]=(const float*)d_in[2*i]; oa.w1[i]=(const float*)d_in[2*i+1]; oa.s[i]=ss[i]; }
        xpath = (const float*)d_in[12];
        sb1   = (const float*)d_in[13];
        sw2   = (const float*)d_in[14];
        sb2   = (const float*)d_in[15];
    }
    const float* fc1w = (const float*)d_in[16];
    const float* fc1b = (const float*)d_in[17];
    const float* whw  = (const float*)d_in[18];
    const float* whb  = (const float*)d_in[19];
    const float* wtw  = (const float*)d_in[20];
    const float* wtb  = (const float*)d_in[21];
    const float* l1w  = (const float*)d_in[22];
    const float* l1b  = (const float*)d_in[23];
    const float* l2w  = (const float*)d_in[24];
    const float* l2b  = (const float*)d_in[25];
    const float* aw1  = (const float*)d_in[26];
    const float* ab1  = (const float*)d_in[27];
    const float* aw2  = (const float*)d_in[28];
    const float* ab2  = (const float*)d_in[29];

    float* out = (float*)d_out;            // fp32 outputs: e_omic(1536) | e_h2(8192*512) | e_g(512)
    float* eh2 = out + 1536;
    float* egp = out + 1536 + 4194304;

    char* wsb = (char*)d_ws;               // ~51.3 MB total
    float* hbuf = (float*)wsb;                          // 16 MB: h (aliased later as enh)
    u16* ehh = (u16*)(wsb + 16777216);                  // 8 MB
    u16* ehl = ehh + 4194304;                           // 8 MB
    u16* eth = ehl + 4194304;                           // 8 MB (aliased later as hm fp32)
    u16* etl = eth + 4194304;                           // 8 MB
    float* mcol = (float*)(wsb + 50331648);             // 512
    float* gbuf = mcol + 512;                           // 8192
    float* vals = gbuf + 8192;                          // 8192*48
    int*   idxb = (int*)(vals + 393216);                // 8192*48
    float* enh  = hbuf;
    float* hm   = (float*)eth;

    omic_kernel<<<6,256,0,stream>>>(oa, sb1, sw2, sb2, out);

    gemm_awt<1><<<dim3(8,128),256,0,stream>>>(xpath, fc1w, fc1b, hbuf, 8192,512,384);
    colmean<<<512,256,0,stream>>>(hbuf, mcol);
    hupd<<<16384,256,0,stream>>>(hbuf, mcol);
    gemm_awt_split<<<dim3(8,128),256,0,stream>>>(hbuf, whw, whb, ehh, ehl);
    gemm_awt_split<<<dim3(8,128),256,0,stream>>>(hbuf, wtw, wtb, eth, etl);
    logits_topk_mfma<<<dim3(64,8),256,0,stream>>>(ehh, ehl, eth, etl, vals, idxb);
    knn_agg<<<2048,256,0,stream>>>(ehh, ehl, eth, etl, vals, idxb, enh);
    lin12<<<dim3(8,128),256,0,stream>>>(ehh, ehl, enh, l1w, l1b, l2w, l2b, eh2);
    gemm_awt<1><<<dim3(4,128),256,0,stream>>>(eh2, aw1, ab1, hm, 8192,256,512);
    att_g<<<2048,256,0,stream>>>(hm, aw2, ab2, gbuf);
    softg<<<1,1024,0,stream>>>(gbuf);
    eg_kernel<<<512,256,0,stream>>>(gbuf, eh2, egp);
}